// Round 11
// baseline (101.573 us; speedup 1.0000x reference)
//
#include <hip/hip_runtime.h>
#include <math.h>

#define TT 128
#define IN_CH 32
#define NPATH 256
#define SIGCH 7380
#define K1 29520
#define N1 512
#define N2 256
#define BG 8

// ---------------- Kernel 1: conv + time-augment + depth-4 signature ----------------
// 1024-thread block per path, 4 groups of 243 threads. Chen time-split:
// group g scans quarter [32g, 32g+32) independently; tree-merge via LDS.
// Output ROW-MAJOR sig[p][7380]: final writes are contiguous/coalesced
// (the old [k][64] layout made every store a 256B-stride scatter with
// cross-XCD partial-line merges).
__global__ __launch_bounds__(1024) void sig_kernel(const float* __restrict__ x,
        const float* __restrict__ cw, const float* __restrict__ cb,
        float* __restrict__ sig /*[256][7380] row-major*/) {
    __shared__ float incT[9][132];
    __shared__ float sb[2][7392];
    const int p = blockIdx.x;
    const int b = p >> 2, oc = p & 3;
    const int tid = threadIdx.x;

    const float4 wv = *(const float4*)(cw + oc * 4);
    const float bias = cb[oc];
    const float* xb = x + (long)b * TT * IN_CH;

    {   // staging: one (t,ch) per thread
        const int t = tid >> 3, ch = tid & 7;
        const float4 xa = *(const float4*)(xb + t * IN_CH + ch * 4);
        float v = xa.x * wv.x + xa.y * wv.y + xa.z * wv.z + xa.w * wv.w + bias;
        if (t > 0) {
            const float4 xm = *(const float4*)(xb + (t - 1) * IN_CH + ch * 4);
            v -= xm.x * wv.x + xm.y * wv.y + xm.z * wv.z + xm.w * wv.w + bias;
        }
        incT[1 + ch][t] = v;
        if (tid < TT) incT[0][tid] = tid ? (1.f / 127.f) : 0.f;
    }
    __syncthreads();

    const int g = tid >> 8;              // group 0..3
    const int gtid = tid & 255;
    const bool act = gtid < 243;
    const int base3 = 3 * gtid;
    const int i1 = base3 / 81;
    const int i2 = (base3 / 9) % 9;
    const int i30 = base3 % 9;           // {0,3,6}
    const int lane = tid & 63;
    const int grow = min(lane, 8);

    float S4[3][9] = {};
    float s3[3] = {0.f, 0.f, 0.f};
    float s2 = 0.f, s1 = 0.f;

#define LD(R, T4) (*(const float4*)&incT[(R)][(T4)])
#define RL(XV, C) __int_as_float(__builtin_amdgcn_readlane(__float_as_int(XV), (C)))
#define STEP(GJ, E1, E2, F0, F1, F2) do { \
    const float t12 = (E1) * (E2); \
    const float s1d2 = s1 * (E2); \
    const float Ak = t12 * (1.f / 24.f) + s1d2 * (1.f / 6.f) + s2 * 0.5f; \
    const float Bk = t12 * (1.f / 6.f) + s1d2 * 0.5f + s2; \
    const float K0 = (F0) * Ak + s3[0]; \
    const float K1v = (F1) * Ak + s3[1]; \
    const float K2v = (F2) * Ak + s3[2]; \
    _Pragma("unroll") \
    for (int c = 0; c < 9; ++c) { \
        const float Ac = RL(GJ, c); \
        S4[0][c] += K0 * Ac; S4[1][c] += K1v * Ac; S4[2][c] += K2v * Ac; \
    } \
    s3[0] += Bk * (F0); s3[1] += Bk * (F1); s3[2] += Bk * (F2); \
    s2 += (E2) * (0.5f * (E1) + s1); \
    s1 += (E1); \
} while (0)

    if (act) {
        const int t0 = g * 32;
        float4 gA = LD(grow, t0), e1v = LD(i1, t0), e2v = LD(i2, t0);
        float4 f0v = LD(i30, t0), f1v = LD(i30 + 1, t0), f2v = LD(i30 + 2, t0);
        for (int j = 0; j < 8; ++j) {
            const int t4 = t0 + (((j + 1) & 7) << 2);     // last prefetch dummy
            const float4 ngA = LD(grow, t4);
            const float4 ne1 = LD(i1, t4), ne2 = LD(i2, t4);
            const float4 nf0 = LD(i30, t4), nf1 = LD(i30 + 1, t4), nf2 = LD(i30 + 2, t4);
            STEP(gA.x, e1v.x, e2v.x, f0v.x, f1v.x, f2v.x);
            STEP(gA.y, e1v.y, e2v.y, f0v.y, f1v.y, f2v.y);
            STEP(gA.z, e1v.z, e2v.z, f0v.z, f1v.z, f2v.z);
            STEP(gA.w, e1v.w, e2v.w, f0v.w, f1v.w, f2v.w);
            gA = ngA; e1v = ne1; e2v = ne2; f0v = nf0; f1v = nf1; f2v = nf2;
        }
    }
#undef STEP
#undef RL
#undef LD

    // ---- Chen tree-merge: (0,1)->0, (2,3)->2, then (0,2)->0 ----
#define WRITE_SIG(D) do { \
    float* d_ = (D); \
    if (i2 == 0 && i30 == 0) d_[i1] = s1; \
    if (i30 == 0) d_[9 + i1 * 9 + i2] = s2; \
    d_[90 + base3] = s3[0]; d_[90 + base3 + 1] = s3[1]; d_[90 + base3 + 2] = s3[2]; \
    _Pragma("unroll") \
    for (int q = 0; q < 3; ++q) \
        _Pragma("unroll") \
        for (int c = 0; c < 9; ++c) d_[819 + (base3 + q) * 9 + c] = S4[q][c]; \
} while (0)

#define MERGE_SIG(S) do { \
    const float* sB_ = (S); \
    float S1B[9]; \
    _Pragma("unroll") \
    for (int c = 0; c < 9; ++c) S1B[c] = sB_[c]; \
    _Pragma("unroll") \
    for (int q = 0; q < 3; ++q) { \
        const int i3q = i30 + q; \
        _Pragma("unroll") \
        for (int c = 0; c < 9; ++c) { \
            S4[q][c] += s3[q] * S1B[c] \
                      + s2 * sB_[9 + i3q * 9 + c] \
                      + s1 * sB_[90 + i2 * 81 + i3q * 9 + c] \
                      + sB_[819 + (base3 + q) * 9 + c]; \
        } \
    } \
    _Pragma("unroll") \
    for (int q = 0; q < 3; ++q) \
        s3[q] += s2 * S1B[i30 + q] + s1 * sB_[9 + i2 * 9 + (i30 + q)] + sB_[90 + base3 + q]; \
    s2 += s1 * S1B[i2] + sB_[9 + i1 * 9 + i2]; \
    s1 += S1B[i1]; \
} while (0)

    if (act && (g == 1 || g == 3)) WRITE_SIG(sb[g >> 1]);
    __syncthreads();
    if (act && g == 0) MERGE_SIG(sb[0]);
    if (act && g == 2) MERGE_SIG(sb[1]);
    __syncthreads();
    if (act && g == 2) WRITE_SIG(sb[0]);
    __syncthreads();
    if (act && g == 0) {
        MERGE_SIG(sb[0]);
        float* sp = sig + (long)p * SIGCH;      // row-major, coalesced
        if (i2 == 0 && i30 == 0) sp[i1] = s1;
        if (i30 == 0) sp[9 + base3 / 9] = s2;
        sp[90 + base3 + 0] = s3[0];
        sp[90 + base3 + 1] = s3[1];
        sp[90 + base3 + 2] = s3[2];
#pragma unroll
        for (int q = 0; q < 3; q++)
#pragma unroll
            for (int l = 0; l < 9; l++)
                sp[819 + (base3 + q) * 9 + l] = S4[q][l];
    }
#undef WRITE_SIG
#undef MERGE_SIG
}

// ---------------- Kernel 2: GEMM1 partials ----------------
// Block = 64 rows x 128 cols, 256 thr / 4 waves (wave = 16 rows, all cols);
// grid = 4 n-quarters x 246 k-chunks = 984 blocks (~4 blocks/CU = ~16 waves/CU)
// so barrier + s_load drains are covered by other blocks. z read from
// ROW-MAJOR sig via wave-uniform s_load_dwordx4 (16 rows x 4 k per half-tile);
// w tile [8][128] LDS dbuf, one conflict-free float2 read/lane/k.
// Per k per lane: 32 FMA vs ~8 LDS cyc -> VALU-bound.
__global__ __launch_bounds__(256) void gemm1_kernel(const float* __restrict__ zsig,
        const float* __restrict__ w0, float* __restrict__ part, int KCH) {
    __shared__ float wt[2][BG][128];
    const int nq = blockIdx.x;            // 0..3
    const int kc = blockIdx.y;
    const int n0 = nq * 128, k0 = kc * KCH;
    const int tid = threadIdx.x;
    const int lane = tid & 63;
    const int wvid = __builtin_amdgcn_readfirstlane(tid >> 6);  // 0..3
    const int r0 = wvid * 16;
    const int c2 = lane * 2;
    const int sk = tid >> 5, sl = tid & 31;   // staging coords

    float4 sA = *(const float4*)(w0 + ((long)k0 + sk) * N1 + n0 + sl * 4);

    float acc[16][2] = {};
    const int NT = KCH / BG;
    int cur = 0;

    for (int t = 0; t < NT; ++t) {
        *(float4*)&wt[cur][sk][sl * 4] = sA;
        __syncthreads();
        if (t + 1 < NT)
            sA = *(const float4*)(w0 + ((long)k0 + (t + 1) * BG + sk) * N1 + n0 + sl * 4);
        const int kk = k0 + t * BG;
#pragma unroll
        for (int h = 0; h < 2; ++h) {
            // 16 rows x 4 k of z -> wave-uniform scalar loads
            float4 z4[16];
#pragma unroll
            for (int r = 0; r < 16; ++r)
                z4[r] = *(const float4*)(zsig + (long)(r0 + r) * K1 + kk + h * 4);
#pragma unroll
            for (int k = 0; k < 4; ++k) {
                const float2 wf = *(const float2*)&wt[cur][h * 4 + k][c2];
#define ZC(R) ((k == 0) ? z4[R].x : (k == 1) ? z4[R].y : (k == 2) ? z4[R].z : z4[R].w)
#pragma unroll
                for (int r = 0; r < 16; ++r) {
                    acc[r][0] += ZC(r) * wf.x;
                    acc[r][1] += ZC(r) * wf.y;
                }
#undef ZC
            }
        }
        cur ^= 1;
    }

    float* pp = part + ((long)kc * 64 + r0) * N1 + n0 + c2;
#pragma unroll
    for (int r = 0; r < 16; r++)
        *(float2*)(pp + (long)r * N1) = make_float2(acc[r][0], acc[r][1]);
}

// ---------------- Kernel 3: reduce partials + bias + sigmoid ----------------
__global__ __launch_bounds__(256) void red1_kernel(const float* __restrict__ part,
        const float* __restrict__ b0v, float* __restrict__ z1, int ksplit) {
    __shared__ float4 red[256];
    const int tid = threadIdx.x;
    const int g = tid & 31, s = tid >> 5;
    const int gg = blockIdx.x * 32 + g;
    const int per = (ksplit + 7) >> 3;
    const int ks = s * per, ke = min(ksplit, ks + per);
    float4 a = make_float4(0.f, 0.f, 0.f, 0.f);
    for (int kc = ks; kc < ke; kc++) {
        float4 pv = *(const float4*)(part + ((long)kc * 8192 + gg) * 4);
        a.x += pv.x; a.y += pv.y; a.z += pv.z; a.w += pv.w;
    }
    red[tid] = a;
    __syncthreads();
    if (tid < 128) { float4 o = red[tid + 128]; red[tid].x += o.x; red[tid].y += o.y; red[tid].z += o.z; red[tid].w += o.w; }
    __syncthreads();
    if (tid < 64) { float4 o = red[tid + 64]; red[tid].x += o.x; red[tid].y += o.y; red[tid].z += o.z; red[tid].w += o.w; }
    __syncthreads();
    if (tid < 32) {
        float4 sum = red[tid];
        float4 o = red[tid + 32];
        sum.x += o.x; sum.y += o.y; sum.z += o.z; sum.w += o.w;
        const float4 bv = *(const float4*)(b0v + (gg & 127) * 4);
        float4 r;
        r.x = 1.f / (1.f + expf(-(sum.x + bv.x)));
        r.y = 1.f / (1.f + expf(-(sum.y + bv.y)));
        r.z = 1.f / (1.f + expf(-(sum.z + bv.z)));
        r.w = 1.f / (1.f + expf(-(sum.w + bv.w)));
        *(float4*)(z1 + gg * 4) = r;
    }
}

// ---------------- Kernel 4: GEMM2 + bias + sigmoid (in-block K-split) ----------------
__global__ __launch_bounds__(256) void gemm2_kernel(const float* __restrict__ z1,
        const float* __restrict__ w1, const float* __restrict__ b1v,
        float* __restrict__ z2) {
    __shared__ float red[256];
    const int m = blockIdx.x >> 2, nq = blockIdx.x & 3;
    const int tid = threadIdx.x;
    const int c = tid & 63, s = tid >> 6;
    const int n = nq * 64 + c;
    const float* zr = z1 + m * N1 + s * 128;
    const float* wr = w1 + (long)(s * 128) * N2 + n;
    float acc = 0.f;
#pragma unroll 16
    for (int k = 0; k < 128; k++) acc += zr[k] * wr[(long)k * N2];
    red[tid] = acc;
    __syncthreads();
    if (tid < 128) red[tid] += red[tid + 128];
    __syncthreads();
    if (tid < 64) {
        float sum = red[tid] + red[tid + 64] + b1v[n];
        z2[m * N2 + n] = 1.f / (1.f + expf(-sum));
    }
}

// ---------------- Kernel 5: GEMM3 + log_softmax ----------------
__global__ __launch_bounds__(64) void head_kernel(const float* __restrict__ z2,
        const float* __restrict__ w2, const float* __restrict__ b2v,
        float* __restrict__ out) {
    const int m = blockIdx.x;
    const int tid = threadIdx.x;
    __shared__ float logits[10];
    if (tid < 10) {
        float s = b2v[tid];
        const float* zr = z2 + m * N2;
#pragma unroll 8
        for (int k = 0; k < N2; k++) s += zr[k] * w2[k * 10 + tid];
        logits[tid] = s;
    }
    __syncthreads();
    if (tid == 0) {
        float mx = logits[0];
        for (int j = 1; j < 10; j++) mx = fmaxf(mx, logits[j]);
        float sum = 0.f;
        for (int j = 0; j < 10; j++) sum += expf(logits[j] - mx);
        const float lse = mx + logf(sum);
        for (int j = 0; j < 10; j++) out[m * 10 + j] = logits[j] - lse;
    }
}

extern "C" void kernel_launch(void* const* d_in, const int* in_sizes, int n_in,
                              void* d_out, int out_size, void* d_ws, size_t ws_size,
                              hipStream_t stream) {
    const float* x  = (const float*)d_in[0];
    const float* cw = (const float*)d_in[1];
    const float* cb = (const float*)d_in[2];
    const float* w0 = (const float*)d_in[3];
    const float* b0 = (const float*)d_in[4];
    const float* w1 = (const float*)d_in[5];
    const float* b1 = (const float*)d_in[6];
    const float* w2 = (const float*)d_in[7];
    const float* b2 = (const float*)d_in[8];

    // tiered K-split by workspace: 29520 = ksplit * KCH, KCH % 8 == 0
    const size_t fixed = (size_t)NPATH * SIGCH + 64 * N1 + 64 * N2;
    int ksplit = 82, kch = 360;
    if (ws_size >= (fixed + (size_t)246 * 64 * N1) * 4)      { ksplit = 246; kch = 120; }
    else if (ws_size >= (fixed + (size_t)123 * 64 * N1) * 4) { ksplit = 123; kch = 240; }

    float* ws   = (float*)d_ws;
    float* sigb = ws;                                // 256 x 7380 row-major
    float* part = sigb + (long)NPATH * SIGCH;        // ksplit*64*512
    float* z1   = part + (long)ksplit * 64 * N1;     // 64*512
    float* z2   = z1 + 64 * N1;                      // 64*256
    float* out  = (float*)d_out;

    sig_kernel<<<NPATH, 1024, 0, stream>>>(x, cw, cb, sigb);
    gemm1_kernel<<<dim3(4, ksplit), 256, 0, stream>>>(sigb, w0, part, kch);
    red1_kernel<<<256, 256, 0, stream>>>(part, b0, z1, ksplit);
    gemm2_kernel<<<256, 256, 0, stream>>>(z1, w1, b1, z2);
    head_kernel<<<64, 64, 0, stream>>>(z2, w2, b2, out);
}